// Round 1
// baseline (1070.692 us; speedup 1.0000x reference)
//
#include <hip/hip_runtime.h>
#include <hip/hip_bf16.h>
#include <math.h>

#define S 2048
#define C 1024
#define H 256
#define HS 2048
#define E 16
#define GNUM 4
#define EPG 4
#define TOPK 4

__device__ __forceinline__ float sigmoidf_(float v) { return 1.f / (1.f + __expf(-v)); }

// ---------------------------------------------------------------------------
// K1: router — one block per token. Computes 16 logits, does grouped sigmoid
// top-k routing, and dispatches (token,k,weight) into per-expert lists.
// ---------------------------------------------------------------------------
__global__ __launch_bounds__(256) void router_kernel(
    const float* __restrict__ x, const float* __restrict__ rw,
    const float* __restrict__ bias, int* __restrict__ counts,
    int* __restrict__ list, float* __restrict__ wlist)
{
    const int s = blockIdx.x;
    __shared__ float xs[C];
    __shared__ float part[E][17];
    __shared__ float logits[E];
    const int tid = threadIdx.x;
    for (int c = tid; c < C; c += 256) xs[c] = x[s * C + c];
    __syncthreads();
    {
        const int e = tid >> 4;   // 0..15
        const int p = tid & 15;   // 0..15
        float sum = 0.f;
        for (int q = 0; q < C / 16; ++q) {
            int c = (q << 4) + p;
            sum += xs[c] * rw[e * C + c];
        }
        part[e][p] = sum;
    }
    __syncthreads();
    if (tid < E) {
        float t = 0.f;
        for (int p = 0; p < 16; ++p) t += part[tid][p];
        logits[tid] = t;
    }
    __syncthreads();
    if (tid == 0) {
        float sc[E], sb[E];
        for (int e2 = 0; e2 < E; ++e2) {
            sc[e2] = 1.f / (1.f + __expf(-logits[e2]));
            sb[e2] = sc[e2] + bias[e2];
        }
        // group score = sum of top-2 biased scores within each group of 4
        float gsc[GNUM];
        for (int g = 0; g < GNUM; ++g) {
            int b_ = g * EPG;
            int m1 = 0; float v1 = sb[b_];
            for (int j = 1; j < EPG; ++j) if (sb[b_ + j] > v1) { v1 = sb[b_ + j]; m1 = j; }
            float v2 = -1e30f;
            for (int j = 0; j < EPG; ++j) if (j != m1 && sb[b_ + j] > v2) v2 = sb[b_ + j];
            gsc[g] = v1 + v2;
        }
        // top-2 groups (ties -> lower index, matching jax.lax.top_k)
        int g1 = 0;
        for (int g = 1; g < GNUM; ++g) if (gsc[g] > gsc[g1]) g1 = g;
        int g2 = (g1 == 0) ? 1 : 0;
        for (int g = 0; g < GNUM; ++g) if (g != g1 && gsc[g] > gsc[g2]) g2 = g;
        // top-4 experts among allowed groups
        bool allowed[E];
        for (int e2 = 0; e2 < E; ++e2) {
            int g = e2 >> 2;
            allowed[e2] = (g == g1) || (g == g2);
        }
        int idx[TOPK]; float wk[TOPK];
        for (int k = 0; k < TOPK; ++k) {
            int best = -1; float bv = -1e30f;
            for (int e2 = 0; e2 < E; ++e2)
                if (allowed[e2] && sb[e2] > bv) { bv = sb[e2]; best = e2; }
            allowed[best] = false;
            idx[k] = best;
            wk[k] = sc[best];   // final weights from UNBIASED scores
        }
        float inv = 1.f / (wk[0] + wk[1] + wk[2] + wk[3] + 1e-20f);
        for (int k = 0; k < TOPK; ++k) {
            int ee = idx[k];
            int pos = atomicAdd(&counts[ee], 1);
            list[ee * S + pos] = s | (k << 16);
            wlist[ee * S + pos] = wk[k] * inv;
        }
    }
}

// ---------------------------------------------------------------------------
// K2: shared expert gate+up, fused SwiGLU. NT GEMM: out[s,h]=sum_c x[s,c]*W[h,c]
// 64x64 tile, 4x4 microtile, TK=16. Writes sh[S,HS].
// ---------------------------------------------------------------------------
__global__ __launch_bounds__(256) void shared_gateup(
    const float* __restrict__ x, const float* __restrict__ gw,
    const float* __restrict__ uw, float* __restrict__ sh)
{
    __shared__ __align__(16) float As[16][68];
    __shared__ __align__(16) float Bg[16][68];
    __shared__ __align__(16) float Bu[16][68];
    const int tid = threadIdx.x;
    const int r0 = blockIdx.y * 64;
    const int c0 = blockIdx.x * 64;
    const int tx = tid & 15, ty = tid >> 4;
    const int la_r = tid >> 2;
    const int la_k = (tid & 3) << 2;
    const float* xrow = x + (r0 + la_r) * C + la_k;
    const float* grow = gw + (c0 + la_r) * C + la_k;
    const float* urow = uw + (c0 + la_r) * C + la_k;
    float ag[4][4] = {{0.f}}, au[4][4] = {{0.f}};
    for (int k0 = 0; k0 < C; k0 += 16) {
        float4 av = *(const float4*)(xrow + k0);
        float4 gv = *(const float4*)(grow + k0);
        float4 uv = *(const float4*)(urow + k0);
        __syncthreads();
        As[la_k + 0][la_r] = av.x; As[la_k + 1][la_r] = av.y; As[la_k + 2][la_r] = av.z; As[la_k + 3][la_r] = av.w;
        Bg[la_k + 0][la_r] = gv.x; Bg[la_k + 1][la_r] = gv.y; Bg[la_k + 2][la_r] = gv.z; Bg[la_k + 3][la_r] = gv.w;
        Bu[la_k + 0][la_r] = uv.x; Bu[la_k + 1][la_r] = uv.y; Bu[la_k + 2][la_r] = uv.z; Bu[la_k + 3][la_r] = uv.w;
        __syncthreads();
#pragma unroll
        for (int kk = 0; kk < 16; ++kk) {
            float4 a4 = *(const float4*)&As[kk][ty << 2];
            float4 g4 = *(const float4*)&Bg[kk][tx << 2];
            float4 u4 = *(const float4*)&Bu[kk][tx << 2];
            float a[4] = {a4.x, a4.y, a4.z, a4.w};
            float g[4] = {g4.x, g4.y, g4.z, g4.w};
            float u[4] = {u4.x, u4.y, u4.z, u4.w};
#pragma unroll
            for (int i = 0; i < 4; ++i)
#pragma unroll
                for (int j = 0; j < 4; ++j) {
                    ag[i][j] += a[i] * g[j];
                    au[i][j] += a[i] * u[j];
                }
        }
    }
#pragma unroll
    for (int i = 0; i < 4; ++i) {
        int row = r0 + (ty << 2) + i;
        float* op = sh + (size_t)row * HS + c0 + (tx << 2);
        float4 o;
        { float g = ag[i][0], u = au[i][0]; o.x = g * sigmoidf_(g) * u; }
        { float g = ag[i][1], u = au[i][1]; o.y = g * sigmoidf_(g) * u; }
        { float g = ag[i][2], u = au[i][2]; o.z = g * sigmoidf_(g) * u; }
        { float g = ag[i][3], u = au[i][3]; o.w = g * sigmoidf_(g) * u; }
        *(float4*)op = o;
    }
}

// ---------------------------------------------------------------------------
// K3: shared expert down-proj, writes out (initializes the output).
// NT GEMM: out[s,c] = sum_h sh[s,h] * sdw[c,h]
// ---------------------------------------------------------------------------
__global__ __launch_bounds__(256) void shared_down(
    const float* __restrict__ sh, const float* __restrict__ dw,
    float* __restrict__ out)
{
    __shared__ __align__(16) float As[16][68];
    __shared__ __align__(16) float Bs[16][68];
    const int tid = threadIdx.x;
    const int r0 = blockIdx.y * 64;
    const int c0 = blockIdx.x * 64;
    const int tx = tid & 15, ty = tid >> 4;
    const int la_r = tid >> 2;
    const int la_k = (tid & 3) << 2;
    const float* arow = sh + (size_t)(r0 + la_r) * HS + la_k;
    const float* brow = dw + (size_t)(c0 + la_r) * HS + la_k;
    float acc[4][4] = {{0.f}};
    for (int k0 = 0; k0 < HS; k0 += 16) {
        float4 av = *(const float4*)(arow + k0);
        float4 bv = *(const float4*)(brow + k0);
        __syncthreads();
        As[la_k + 0][la_r] = av.x; As[la_k + 1][la_r] = av.y; As[la_k + 2][la_r] = av.z; As[la_k + 3][la_r] = av.w;
        Bs[la_k + 0][la_r] = bv.x; Bs[la_k + 1][la_r] = bv.y; Bs[la_k + 2][la_r] = bv.z; Bs[la_k + 3][la_r] = bv.w;
        __syncthreads();
#pragma unroll
        for (int kk = 0; kk < 16; ++kk) {
            float4 a4 = *(const float4*)&As[kk][ty << 2];
            float4 b4 = *(const float4*)&Bs[kk][tx << 2];
            float a[4] = {a4.x, a4.y, a4.z, a4.w};
            float b[4] = {b4.x, b4.y, b4.z, b4.w};
#pragma unroll
            for (int i = 0; i < 4; ++i)
#pragma unroll
                for (int j = 0; j < 4; ++j) acc[i][j] += a[i] * b[j];
        }
    }
#pragma unroll
    for (int i = 0; i < 4; ++i) {
        int row = r0 + (ty << 2) + i;
        float4 o = {acc[i][0], acc[i][1], acc[i][2], acc[i][3]};
        *(float4*)(out + (size_t)row * C + c0 + (tx << 2)) = o;
    }
}

// ---------------------------------------------------------------------------
// K4: routed gate+up over gathered token tiles, fused SwiGLU * combine weight.
// NN GEMM: h[i,hh] = sum_c x[tok_i,c] * gw[e][c,hh]. Writes hbuf[s*K+k][H].
// ---------------------------------------------------------------------------
__global__ __launch_bounds__(256) void routed_gateup(
    const float* __restrict__ x, const float* __restrict__ gate_w,
    const float* __restrict__ up_w, const int* __restrict__ counts,
    const int* __restrict__ list, const float* __restrict__ wlist,
    float* __restrict__ hbuf)
{
    const int e = blockIdx.z;
    const int n = counts[e];
    const int t0 = blockIdx.x * 64;
    if (t0 >= n) return;
    const int h0 = blockIdx.y * 64;
    __shared__ int toks[64];
    __shared__ int hrow[64];
    __shared__ float wv[64];
    __shared__ __align__(16) float As[16][68];
    __shared__ __align__(16) float Bg[16][68];
    __shared__ __align__(16) float Bu[16][68];
    const int tid = threadIdx.x;
    if (tid < 64) {
        int p = t0 + tid;
        if (p < n) {
            int pk = list[e * S + p];
            int s_ = pk & 0xFFFF;
            toks[tid] = s_;
            hrow[tid] = s_ * TOPK + (pk >> 16);
            wv[tid] = wlist[e * S + p];
        } else {
            toks[tid] = 0; hrow[tid] = 0; wv[tid] = 0.f;
        }
    }
    __syncthreads();
    const int tx = tid & 15, ty = tid >> 4;
    const int la_r = tid >> 2;
    const int la_k = (tid & 3) << 2;
    const int lb_j = tid & 63;
    const int lb_k = tid >> 6;   // 0..3
    const float* xrow = x + (size_t)toks[la_r] * C + la_k;
    const float* gwe = gate_w + (size_t)e * C * H;
    const float* uwe = up_w + (size_t)e * C * H;
    float ag[4][4] = {{0.f}}, au[4][4] = {{0.f}};
    for (int k0 = 0; k0 < C; k0 += 16) {
        float4 av = *(const float4*)(xrow + k0);
        float bgv[4], buv[4];
#pragma unroll
        for (int q = 0; q < 4; ++q) {
            int kk = lb_k + (q << 2);
            bgv[q] = gwe[(size_t)(k0 + kk) * H + h0 + lb_j];
            buv[q] = uwe[(size_t)(k0 + kk) * H + h0 + lb_j];
        }
        __syncthreads();
        As[la_k + 0][la_r] = av.x; As[la_k + 1][la_r] = av.y; As[la_k + 2][la_r] = av.z; As[la_k + 3][la_r] = av.w;
#pragma unroll
        for (int q = 0; q < 4; ++q) {
            int kk = lb_k + (q << 2);
            Bg[kk][lb_j] = bgv[q];
            Bu[kk][lb_j] = buv[q];
        }
        __syncthreads();
#pragma unroll
        for (int kk = 0; kk < 16; ++kk) {
            float4 a4 = *(const float4*)&As[kk][ty << 2];
            float4 g4 = *(const float4*)&Bg[kk][tx << 2];
            float4 u4 = *(const float4*)&Bu[kk][tx << 2];
            float a[4] = {a4.x, a4.y, a4.z, a4.w};
            float g[4] = {g4.x, g4.y, g4.z, g4.w};
            float u[4] = {u4.x, u4.y, u4.z, u4.w};
#pragma unroll
            for (int i = 0; i < 4; ++i)
#pragma unroll
                for (int j = 0; j < 4; ++j) {
                    ag[i][j] += a[i] * g[j];
                    au[i][j] += a[i] * u[j];
                }
        }
    }
#pragma unroll
    for (int i = 0; i < 4; ++i) {
        int li = (ty << 2) + i;
        if (t0 + li < n) {
            float w_ = wv[li];
            int row = hrow[li];
            float4 o;
            { float g = ag[i][0], u = au[i][0]; o.x = w_ * g * sigmoidf_(g) * u; }
            { float g = ag[i][1], u = au[i][1]; o.y = w_ * g * sigmoidf_(g) * u; }
            { float g = ag[i][2], u = au[i][2]; o.z = w_ * g * sigmoidf_(g) * u; }
            { float g = ag[i][3], u = au[i][3]; o.w = w_ * g * sigmoidf_(g) * u; }
            *(float4*)(hbuf + (size_t)row * H + h0 + (tx << 2)) = o;
        }
    }
}

// ---------------------------------------------------------------------------
// K5: routed down-proj over gathered tiles; atomic accumulate into out.
// NN GEMM: y[i,c] = sum_h hbuf[row_i,h] * dw[e][h,c]
// ---------------------------------------------------------------------------
__global__ __launch_bounds__(256) void routed_down(
    const float* __restrict__ hbuf, const float* __restrict__ down_w,
    const int* __restrict__ counts, const int* __restrict__ list,
    float* __restrict__ out)
{
    const int e = blockIdx.z;
    const int n = counts[e];
    const int t0 = blockIdx.x * 64;
    if (t0 >= n) return;
    const int c0 = blockIdx.y * 64;
    __shared__ int toks[64];
    __shared__ int hrow[64];
    __shared__ __align__(16) float As[16][68];
    __shared__ __align__(16) float Bs[16][68];
    const int tid = threadIdx.x;
    if (tid < 64) {
        int p = t0 + tid;
        if (p < n) {
            int pk = list[e * S + p];
            int s_ = pk & 0xFFFF;
            toks[tid] = s_;
            hrow[tid] = s_ * TOPK + (pk >> 16);
        } else {
            toks[tid] = 0; hrow[tid] = 0;
        }
    }
    __syncthreads();
    const int tx = tid & 15, ty = tid >> 4;
    const int la_r = tid >> 2;
    const int la_k = (tid & 3) << 2;
    const int lb_j = tid & 63;
    const int lb_k = tid >> 6;
    const float* arow = hbuf + (size_t)hrow[la_r] * H + la_k;
    const float* dwe = down_w + (size_t)e * H * C;
    float acc[4][4] = {{0.f}};
    for (int k0 = 0; k0 < H; k0 += 16) {
        float4 av = *(const float4*)(arow + k0);
        float bv[4];
#pragma unroll
        for (int q = 0; q < 4; ++q) {
            int kk = lb_k + (q << 2);
            bv[q] = dwe[(size_t)(k0 + kk) * C + c0 + lb_j];
        }
        __syncthreads();
        As[la_k + 0][la_r] = av.x; As[la_k + 1][la_r] = av.y; As[la_k + 2][la_r] = av.z; As[la_k + 3][la_r] = av.w;
#pragma unroll
        for (int q = 0; q < 4; ++q) {
            int kk = lb_k + (q << 2);
            Bs[kk][lb_j] = bv[q];
        }
        __syncthreads();
#pragma unroll
        for (int kk = 0; kk < 16; ++kk) {
            float4 a4 = *(const float4*)&As[kk][ty << 2];
            float4 b4 = *(const float4*)&Bs[kk][tx << 2];
            float a[4] = {a4.x, a4.y, a4.z, a4.w};
            float b[4] = {b4.x, b4.y, b4.z, b4.w};
#pragma unroll
            for (int i = 0; i < 4; ++i)
#pragma unroll
                for (int j = 0; j < 4; ++j) acc[i][j] += a[i] * b[j];
        }
    }
#pragma unroll
    for (int i = 0; i < 4; ++i) {
        int li = (ty << 2) + i;
        if (t0 + li < n) {
            int tok = toks[li];
            float* op = out + (size_t)tok * C + c0 + (tx << 2);
#pragma unroll
            for (int j = 0; j < 4; ++j) atomicAdd(op + j, acc[i][j]);
        }
    }
}

// ---------------------------------------------------------------------------
extern "C" void kernel_launch(void* const* d_in, const int* in_sizes, int n_in,
                              void* d_out, int out_size, void* d_ws, size_t ws_size,
                              hipStream_t stream)
{
    const float* x        = (const float*)d_in[0];
    const float* router_w = (const float*)d_in[1];
    const float* bias     = (const float*)d_in[2];
    const float* gate_w   = (const float*)d_in[3];
    const float* up_w     = (const float*)d_in[4];
    const float* down_w   = (const float*)d_in[5];
    const float* sgw      = (const float*)d_in[6];
    const float* suw      = (const float*)d_in[7];
    const float* sdw      = (const float*)d_in[8];
    float* out = (float*)d_out;

    char* ws = (char*)d_ws;
    int*   counts = (int*)ws;                                   // 64 B (pad to 256)
    int*   list   = (int*)(ws + 256);                           // E*S ints   = 128 KiB
    float* wlist  = (float*)(ws + 256 + E * S * 4);             // E*S floats = 128 KiB
    float* hbuf   = (float*)(ws + 256 + 2 * E * S * 4);         // S*K*H      = 8 MiB
    float* sh     = (float*)(ws + 256 + 2 * E * S * 4 + (size_t)S * TOPK * H * 4); // S*HS = 16 MiB

    hipMemsetAsync(counts, 0, E * sizeof(int), stream);
    router_kernel<<<S, 256, 0, stream>>>(x, router_w, bias, counts, list, wlist);
    shared_gateup<<<dim3(HS / 64, S / 64), 256, 0, stream>>>(x, sgw, suw, sh);
    shared_down<<<dim3(C / 64, S / 64), 256, 0, stream>>>(sh, sdw, out);
    routed_gateup<<<dim3(S / 64, H / 64, E), 256, 0, stream>>>(x, gate_w, up_w, counts, list, wlist, hbuf);
    routed_down<<<dim3(S / 64, C / 64, E), 256, 0, stream>>>(hbuf, down_w, counts, list, out);
}

// Round 2
// 402.291 us; speedup vs baseline: 2.6615x; 2.6615x over previous
//
#include <hip/hip_runtime.h>
#include <hip/hip_bf16.h>
#include <math.h>

#define S 2048
#define CDIM 1024
#define H 256
#define HS 2048
#define E 16
#define GNUM 4
#define EPG 4
#define TOPK 4

typedef __attribute__((ext_vector_type(8))) short bfrag_t;   // 8 bf16 = 4 VGPRs
typedef __attribute__((ext_vector_type(4))) float facc_t;    // 4 fp32 acc
typedef __attribute__((ext_vector_type(4))) unsigned int u32x4;

__device__ __forceinline__ float sigmoidf_(float v) { return 1.f / (1.f + __expf(-v)); }

__device__ __forceinline__ unsigned short f2bf(float f) {
    union { float f; unsigned u; } v; v.f = f;
    unsigned r = v.u + 0x7FFFu + ((v.u >> 16) & 1u);   // round-to-nearest-even
    return (unsigned short)(r >> 16);
}
__device__ __forceinline__ float bf2f(unsigned short u) {
    union { unsigned u; float f; } v; v.u = ((unsigned)u) << 16; return v.f;
}

// ---------------------------------------------------------------------------
// K1: router — fp32, unchanged (routing must stay exact).
// ---------------------------------------------------------------------------
__global__ __launch_bounds__(256) void router_kernel(
    const float* __restrict__ x, const float* __restrict__ rw,
    const float* __restrict__ bias, int* __restrict__ counts,
    int* __restrict__ list, float* __restrict__ wlist)
{
    const int s = blockIdx.x;
    __shared__ float xs[CDIM];
    __shared__ float part[E][17];
    __shared__ float logits[E];
    const int tid = threadIdx.x;
    for (int c = tid; c < CDIM; c += 256) xs[c] = x[s * CDIM + c];
    __syncthreads();
    {
        const int e = tid >> 4;
        const int p = tid & 15;
        float sum = 0.f;
        for (int q = 0; q < CDIM / 16; ++q) {
            int c = (q << 4) + p;
            sum += xs[c] * rw[e * CDIM + c];
        }
        part[e][p] = sum;
    }
    __syncthreads();
    if (tid < E) {
        float t = 0.f;
        for (int p = 0; p < 16; ++p) t += part[tid][p];
        logits[tid] = t;
    }
    __syncthreads();
    if (tid == 0) {
        float sc[E], sb[E];
        for (int e2 = 0; e2 < E; ++e2) {
            sc[e2] = 1.f / (1.f + __expf(-logits[e2]));
            sb[e2] = sc[e2] + bias[e2];
        }
        float gsc[GNUM];
        for (int g = 0; g < GNUM; ++g) {
            int b_ = g * EPG;
            int m1 = 0; float v1 = sb[b_];
            for (int j = 1; j < EPG; ++j) if (sb[b_ + j] > v1) { v1 = sb[b_ + j]; m1 = j; }
            float v2 = -1e30f;
            for (int j = 0; j < EPG; ++j) if (j != m1 && sb[b_ + j] > v2) v2 = sb[b_ + j];
            gsc[g] = v1 + v2;
        }
        int g1 = 0;
        for (int g = 1; g < GNUM; ++g) if (gsc[g] > gsc[g1]) g1 = g;
        int g2 = (g1 == 0) ? 1 : 0;
        for (int g = 0; g < GNUM; ++g) if (g != g1 && gsc[g] > gsc[g2]) g2 = g;
        bool allowed[E];
        for (int e2 = 0; e2 < E; ++e2) {
            int g = e2 >> 2;
            allowed[e2] = (g == g1) || (g == g2);
        }
        int idx[TOPK]; float wk[TOPK];
        for (int k = 0; k < TOPK; ++k) {
            int best = -1; float bv = -1e30f;
            for (int e2 = 0; e2 < E; ++e2)
                if (allowed[e2] && sb[e2] > bv) { bv = sb[e2]; best = e2; }
            allowed[best] = false;
            idx[k] = best;
            wk[k] = sc[best];
        }
        float inv = 1.f / (wk[0] + wk[1] + wk[2] + wk[3] + 1e-20f);
        for (int k = 0; k < TOPK; ++k) {
            int ee = idx[k];
            int pos = atomicAdd(&counts[ee], 1);
            list[ee * S + pos] = s | (k << 16);
            wlist[ee * S + pos] = wk[k] * inv;
        }
    }
}

// ---------------------------------------------------------------------------
// K2: elementwise fp32 -> bf16 cast (vectorized x4)
// ---------------------------------------------------------------------------
__global__ __launch_bounds__(256) void cast_bf16(
    const float4* __restrict__ src, unsigned short* __restrict__ dst, int n4)
{
    int i = blockIdx.x * 256 + threadIdx.x;
    if (i >= n4) return;
    float4 v = src[i];
    unsigned long long p = (unsigned long long)f2bf(v.x)
                         | ((unsigned long long)f2bf(v.y) << 16)
                         | ((unsigned long long)f2bf(v.z) << 32)
                         | ((unsigned long long)f2bf(v.w) << 48);
    ((unsigned long long*)dst)[i] = p;
}

// ---------------------------------------------------------------------------
// K3: tiled transpose + cast: src [z][R][Cc] fp32 -> dst [z][Cc][R] bf16
// ---------------------------------------------------------------------------
__global__ __launch_bounds__(256) void transpose_cast(
    const float* __restrict__ src, unsigned short* __restrict__ dst, int R, int Cc)
{
    __shared__ float t[32][33];
    const size_t mo = (size_t)blockIdx.z * R * Cc;
    src += mo; dst += mo;
    const int c0 = blockIdx.x * 32, r0 = blockIdx.y * 32;
    const int tx = threadIdx.x, ty = threadIdx.y;  // (32, 8)
#pragma unroll
    for (int i = 0; i < 32; i += 8)
        t[ty + i][tx] = src[(size_t)(r0 + ty + i) * Cc + c0 + tx];
    __syncthreads();
#pragma unroll
    for (int i = 0; i < 32; i += 8)
        dst[(size_t)(c0 + ty + i) * R + r0 + tx] = f2bf(t[tx][ty + i]);
}

// ---------------------------------------------------------------------------
// MFMA GEMM tiles: BM=128, BN=64, BK=32, block=256 (4 waves, 2x2), each wave
// 64x32 = 4x2 mfma_f32_16x16x32_bf16 tiles. LDS row stride 40 shorts (80 B,
// 16B-aligned b128 reads, worst 2-way banks = free).
// A frag: lane holds A[m=lane&15][k=(lane>>4)*8 .. +8]; B^T frag identical.
// C/D: col=lane&15, row=(lane>>4)*4+reg.
// ---------------------------------------------------------------------------

// K4: shared expert gate+up fused SwiGLU -> shb bf16 [S][HS]
__global__ __launch_bounds__(256) void gemm_shared_gateup(
    const unsigned short* __restrict__ xb, const unsigned short* __restrict__ gb,
    const unsigned short* __restrict__ ub, unsigned short* __restrict__ shb)
{
    __shared__ __align__(16) unsigned short As[128][40];
    __shared__ __align__(16) unsigned short Bg[64][40];
    __shared__ __align__(16) unsigned short Bu[64][40];
    const int tid = threadIdx.x;
    const int r0 = blockIdx.y * 128;
    const int c0 = blockIdx.x * 64;
    const int lane = tid & 63, w = tid >> 6;
    const int wr = (w >> 1) * 64, wc = (w & 1) * 32;
    const int l15 = lane & 15, q = lane >> 4;
    const int srow = tid >> 2, sseg = tid & 3;
    const unsigned short* Ag = xb + (size_t)(r0 + srow) * CDIM + sseg * 8;
    const unsigned short* Gg = gb + (size_t)(c0 + srow) * CDIM + sseg * 8;
    const unsigned short* Ug = ub + (size_t)(c0 + srow) * CDIM + sseg * 8;
    facc_t accg[4][2], accu[4][2];
#pragma unroll
    for (int i = 0; i < 4; ++i)
#pragma unroll
        for (int j = 0; j < 2; ++j) { accg[i][j] = 0.f; accu[i][j] = 0.f; }
    for (int k0 = 0; k0 < CDIM; k0 += 32) {
        u32x4 a1 = *(const u32x4*)(Ag + k0);
        u32x4 a2 = *(const u32x4*)(Ag + (size_t)64 * CDIM + k0);
        u32x4 g1 = *(const u32x4*)(Gg + k0);
        u32x4 u1 = *(const u32x4*)(Ug + k0);
        __syncthreads();
        *(u32x4*)&As[srow][sseg * 8] = a1;
        *(u32x4*)&As[srow + 64][sseg * 8] = a2;
        *(u32x4*)&Bg[srow][sseg * 8] = g1;
        *(u32x4*)&Bu[srow][sseg * 8] = u1;
        __syncthreads();
        bfrag_t af[4], gf[2], uf[2];
#pragma unroll
        for (int i = 0; i < 4; ++i) af[i] = *(const bfrag_t*)&As[wr + i * 16 + l15][q * 8];
#pragma unroll
        for (int j = 0; j < 2; ++j) {
            gf[j] = *(const bfrag_t*)&Bg[wc + j * 16 + l15][q * 8];
            uf[j] = *(const bfrag_t*)&Bu[wc + j * 16 + l15][q * 8];
        }
#pragma unroll
        for (int i = 0; i < 4; ++i)
#pragma unroll
            for (int j = 0; j < 2; ++j) {
                accg[i][j] = __builtin_amdgcn_mfma_f32_16x16x32_bf16(af[i], gf[j], accg[i][j], 0, 0, 0);
                accu[i][j] = __builtin_amdgcn_mfma_f32_16x16x32_bf16(af[i], uf[j], accu[i][j], 0, 0, 0);
            }
    }
#pragma unroll
    for (int i = 0; i < 4; ++i)
#pragma unroll
        for (int j = 0; j < 2; ++j)
#pragma unroll
            for (int r = 0; r < 4; ++r) {
                int row = r0 + wr + i * 16 + q * 4 + r;
                int col = c0 + wc + j * 16 + l15;
                float g = accg[i][j][r], u = accu[i][j][r];
                shb[(size_t)row * HS + col] = f2bf(g * sigmoidf_(g) * u);
            }
}

// K5: shared expert down-proj -> out fp32 [S][CDIM] (initializes out)
__global__ __launch_bounds__(256) void gemm_shared_down(
    const unsigned short* __restrict__ shb, const unsigned short* __restrict__ db,
    float* __restrict__ out)
{
    __shared__ __align__(16) unsigned short As[128][40];
    __shared__ __align__(16) unsigned short Bs[64][40];
    const int tid = threadIdx.x;
    const int r0 = blockIdx.y * 128;
    const int c0 = blockIdx.x * 64;
    const int lane = tid & 63, w = tid >> 6;
    const int wr = (w >> 1) * 64, wc = (w & 1) * 32;
    const int l15 = lane & 15, q = lane >> 4;
    const int srow = tid >> 2, sseg = tid & 3;
    const unsigned short* Ag = shb + (size_t)(r0 + srow) * HS + sseg * 8;
    const unsigned short* Bgp = db + (size_t)(c0 + srow) * HS + sseg * 8;
    facc_t acc[4][2];
#pragma unroll
    for (int i = 0; i < 4; ++i)
#pragma unroll
        for (int j = 0; j < 2; ++j) acc[i][j] = 0.f;
    for (int k0 = 0; k0 < HS; k0 += 32) {
        u32x4 a1 = *(const u32x4*)(Ag + k0);
        u32x4 a2 = *(const u32x4*)(Ag + (size_t)64 * HS + k0);
        u32x4 b1 = *(const u32x4*)(Bgp + k0);
        __syncthreads();
        *(u32x4*)&As[srow][sseg * 8] = a1;
        *(u32x4*)&As[srow + 64][sseg * 8] = a2;
        *(u32x4*)&Bs[srow][sseg * 8] = b1;
        __syncthreads();
        bfrag_t af[4], bf[2];
#pragma unroll
        for (int i = 0; i < 4; ++i) af[i] = *(const bfrag_t*)&As[wr + i * 16 + l15][q * 8];
#pragma unroll
        for (int j = 0; j < 2; ++j) bf[j] = *(const bfrag_t*)&Bs[wc + j * 16 + l15][q * 8];
#pragma unroll
        for (int i = 0; i < 4; ++i)
#pragma unroll
            for (int j = 0; j < 2; ++j)
                acc[i][j] = __builtin_amdgcn_mfma_f32_16x16x32_bf16(af[i], bf[j], acc[i][j], 0, 0, 0);
    }
#pragma unroll
    for (int i = 0; i < 4; ++i)
#pragma unroll
        for (int j = 0; j < 2; ++j)
#pragma unroll
            for (int r = 0; r < 4; ++r) {
                int row = r0 + wr + i * 16 + q * 4 + r;
                int col = c0 + wc + j * 16 + l15;
                out[(size_t)row * CDIM + col] = acc[i][j][r];
            }
}

// K6: routed gate+up fused, gathered A rows, weighted SwiGLU -> hbuf bf16 [S*4][H]
__global__ __launch_bounds__(256) void gemm_routed_gateup(
    const unsigned short* __restrict__ xb, const unsigned short* __restrict__ gwT,
    const unsigned short* __restrict__ uwT, const int* __restrict__ counts,
    const int* __restrict__ list, const float* __restrict__ wlist,
    unsigned short* __restrict__ hbuf)
{
    const int e = blockIdx.z;
    const int n = counts[e];
    const int t0 = blockIdx.x * 128;
    if (t0 >= n) return;
    const int h0 = blockIdx.y * 64;
    __shared__ int toks[128];
    __shared__ int hrw[128];
    __shared__ float wv[128];
    __shared__ __align__(16) unsigned short As[128][40];
    __shared__ __align__(16) unsigned short Bg[64][40];
    __shared__ __align__(16) unsigned short Bu[64][40];
    const int tid = threadIdx.x;
    if (tid < 128) {
        int p = t0 + tid;
        if (p < n) {
            int pk = list[e * S + p];
            toks[tid] = pk & 0xFFFF;
            hrw[tid] = (pk & 0xFFFF) * TOPK + (pk >> 16);
            wv[tid] = wlist[e * S + p];
        } else { toks[tid] = 0; hrw[tid] = 0; wv[tid] = 0.f; }
    }
    __syncthreads();
    const int lane = tid & 63, w = tid >> 6;
    const int wr = (w >> 1) * 64, wc = (w & 1) * 32;
    const int l15 = lane & 15, q = lane >> 4;
    const int srow = tid >> 2, sseg = tid & 3;
    const unsigned short* A1 = xb + (size_t)toks[srow] * CDIM + sseg * 8;
    const unsigned short* A2 = xb + (size_t)toks[srow + 64] * CDIM + sseg * 8;
    const unsigned short* G1 = gwT + (size_t)e * H * CDIM + (size_t)(h0 + srow) * CDIM + sseg * 8;
    const unsigned short* U1 = uwT + (size_t)e * H * CDIM + (size_t)(h0 + srow) * CDIM + sseg * 8;
    facc_t accg[4][2], accu[4][2];
#pragma unroll
    for (int i = 0; i < 4; ++i)
#pragma unroll
        for (int j = 0; j < 2; ++j) { accg[i][j] = 0.f; accu[i][j] = 0.f; }
    for (int k0 = 0; k0 < CDIM; k0 += 32) {
        u32x4 a1 = *(const u32x4*)(A1 + k0);
        u32x4 a2 = *(const u32x4*)(A2 + k0);
        u32x4 g1 = *(const u32x4*)(G1 + k0);
        u32x4 u1 = *(const u32x4*)(U1 + k0);
        __syncthreads();
        *(u32x4*)&As[srow][sseg * 8] = a1;
        *(u32x4*)&As[srow + 64][sseg * 8] = a2;
        *(u32x4*)&Bg[srow][sseg * 8] = g1;
        *(u32x4*)&Bu[srow][sseg * 8] = u1;
        __syncthreads();
        bfrag_t af[4], gf[2], uf[2];
#pragma unroll
        for (int i = 0; i < 4; ++i) af[i] = *(const bfrag_t*)&As[wr + i * 16 + l15][q * 8];
#pragma unroll
        for (int j = 0; j < 2; ++j) {
            gf[j] = *(const bfrag_t*)&Bg[wc + j * 16 + l15][q * 8];
            uf[j] = *(const bfrag_t*)&Bu[wc + j * 16 + l15][q * 8];
        }
#pragma unroll
        for (int i = 0; i < 4; ++i)
#pragma unroll
            for (int j = 0; j < 2; ++j) {
                accg[i][j] = __builtin_amdgcn_mfma_f32_16x16x32_bf16(af[i], gf[j], accg[i][j], 0, 0, 0);
                accu[i][j] = __builtin_amdgcn_mfma_f32_16x16x32_bf16(af[i], uf[j], accu[i][j], 0, 0, 0);
            }
    }
#pragma unroll
    for (int i = 0; i < 4; ++i)
#pragma unroll
        for (int j = 0; j < 2; ++j)
#pragma unroll
            for (int r = 0; r < 4; ++r) {
                int li = wr + i * 16 + q * 4 + r;
                if (t0 + li < n) {
                    int col = h0 + wc + j * 16 + l15;
                    float g = accg[i][j][r], u = accu[i][j][r];
                    hbuf[(size_t)hrw[li] * H + col] = f2bf(wv[li] * g * sigmoidf_(g) * u);
                }
            }
}

// K7: routed down-proj, gathered A rows from hbuf -> dbuf bf16 [S*4][CDIM]
__global__ __launch_bounds__(256) void gemm_routed_down(
    const unsigned short* __restrict__ hbuf, const unsigned short* __restrict__ dwT,
    const int* __restrict__ counts, const int* __restrict__ list,
    unsigned short* __restrict__ dbuf)
{
    const int e = blockIdx.z;
    const int n = counts[e];
    const int t0 = blockIdx.x * 128;
    if (t0 >= n) return;
    const int c0 = blockIdx.y * 64;
    __shared__ int hrw[128];
    __shared__ __align__(16) unsigned short As[128][40];
    __shared__ __align__(16) unsigned short Bs[64][40];
    const int tid = threadIdx.x;
    if (tid < 128) {
        int p = t0 + tid;
        int pk = (p < n) ? list[e * S + p] : 0;
        hrw[tid] = (pk & 0xFFFF) * TOPK + (pk >> 16);
    }
    __syncthreads();
    const int lane = tid & 63, w = tid >> 6;
    const int wr = (w >> 1) * 64, wc = (w & 1) * 32;
    const int l15 = lane & 15, q = lane >> 4;
    const int srow = tid >> 2, sseg = tid & 3;
    const unsigned short* A1 = hbuf + (size_t)hrw[srow] * H + sseg * 8;
    const unsigned short* A2 = hbuf + (size_t)hrw[srow + 64] * H + sseg * 8;
    const unsigned short* B1 = dwT + (size_t)e * CDIM * H + (size_t)(c0 + srow) * H + sseg * 8;
    facc_t acc[4][2];
#pragma unroll
    for (int i = 0; i < 4; ++i)
#pragma unroll
        for (int j = 0; j < 2; ++j) acc[i][j] = 0.f;
    for (int k0 = 0; k0 < H; k0 += 32) {
        u32x4 a1 = *(const u32x4*)(A1 + k0);
        u32x4 a2 = *(const u32x4*)(A2 + k0);
        u32x4 b1 = *(const u32x4*)(B1 + k0);
        __syncthreads();
        *(u32x4*)&As[srow][sseg * 8] = a1;
        *(u32x4*)&As[srow + 64][sseg * 8] = a2;
        *(u32x4*)&Bs[srow][sseg * 8] = b1;
        __syncthreads();
        bfrag_t af[4], bf[2];
#pragma unroll
        for (int i = 0; i < 4; ++i) af[i] = *(const bfrag_t*)&As[wr + i * 16 + l15][q * 8];
#pragma unroll
        for (int j = 0; j < 2; ++j) bf[j] = *(const bfrag_t*)&Bs[wc + j * 16 + l15][q * 8];
#pragma unroll
        for (int i = 0; i < 4; ++i)
#pragma unroll
            for (int j = 0; j < 2; ++j)
                acc[i][j] = __builtin_amdgcn_mfma_f32_16x16x32_bf16(af[i], bf[j], acc[i][j], 0, 0, 0);
    }
#pragma unroll
    for (int i = 0; i < 4; ++i)
#pragma unroll
        for (int j = 0; j < 2; ++j)
#pragma unroll
            for (int r = 0; r < 4; ++r) {
                int li = wr + i * 16 + q * 4 + r;
                if (t0 + li < n) {
                    int col = c0 + wc + j * 16 + l15;
                    dbuf[(size_t)hrw[li] * CDIM + col] = f2bf(acc[i][j][r]);
                }
            }
}

// K8: out[s,c] += sum_k dbuf[s*4+k, c]  (out already holds shared-expert result)
__global__ __launch_bounds__(256) void final_add(
    float* __restrict__ out, const unsigned short* __restrict__ dbuf)
{
    int i = blockIdx.x * 256 + threadIdx.x;   // 8 floats per thread
    int s = i >> 7;                            // CDIM/8 = 128 chunks/row
    int co = (i & 127) << 3;
    float* op = out + (size_t)s * CDIM + co;
    float4 o0 = *(float4*)op, o1 = *(float4*)(op + 4);
#pragma unroll
    for (int k = 0; k < TOPK; ++k) {
        const unsigned short* dp = dbuf + ((size_t)s * TOPK + k) * CDIM + co;
        u32x4 v = *(const u32x4*)dp;
        o0.x += bf2f((unsigned short)(v.x));        o0.y += bf2f((unsigned short)(v.x >> 16));
        o0.z += bf2f((unsigned short)(v.y));        o0.w += bf2f((unsigned short)(v.y >> 16));
        o1.x += bf2f((unsigned short)(v.z));        o1.y += bf2f((unsigned short)(v.z >> 16));
        o1.z += bf2f((unsigned short)(v.w));        o1.w += bf2f((unsigned short)(v.w >> 16));
    }
    *(float4*)op = o0; *(float4*)(op + 4) = o1;
}

// ---------------------------------------------------------------------------
extern "C" void kernel_launch(void* const* d_in, const int* in_sizes, int n_in,
                              void* d_out, int out_size, void* d_ws, size_t ws_size,
                              hipStream_t stream)
{
    const float* x        = (const float*)d_in[0];
    const float* router_w = (const float*)d_in[1];
    const float* bias     = (const float*)d_in[2];
    const float* gate_w   = (const float*)d_in[3];
    const float* up_w     = (const float*)d_in[4];
    const float* down_w   = (const float*)d_in[5];
    const float* sgw      = (const float*)d_in[6];
    const float* suw      = (const float*)d_in[7];
    const float* sdw      = (const float*)d_in[8];
    float* out = (float*)d_out;

    char* ws = (char*)d_ws;
    size_t off = 0;
    int* counts = (int*)(ws + off);            off += 256;
    int* list   = (int*)(ws + off);            off += (size_t)E * S * 4;
    float* wlist = (float*)(ws + off);         off += (size_t)E * S * 4;
    unsigned short* xb  = (unsigned short*)(ws + off); off += (size_t)S * CDIM * 2;
    unsigned short* sgb = (unsigned short*)(ws + off); off += (size_t)HS * CDIM * 2;
    unsigned short* sub = (unsigned short*)(ws + off); off += (size_t)HS * CDIM * 2;
    unsigned short* sdb = (unsigned short*)(ws + off); off += (size_t)CDIM * HS * 2;
    unsigned short* gwT = (unsigned short*)(ws + off); off += (size_t)E * H * CDIM * 2;
    unsigned short* uwT = (unsigned short*)(ws + off); off += (size_t)E * H * CDIM * 2;
    unsigned short* dwT = (unsigned short*)(ws + off); off += (size_t)E * CDIM * H * 2;
    unsigned short* shb = (unsigned short*)(ws + off); off += (size_t)S * HS * 2;
    unsigned short* hbuf = (unsigned short*)(ws + off); off += (size_t)S * TOPK * H * 2;
    unsigned short* dbuf = (unsigned short*)(ws + off); off += (size_t)S * TOPK * CDIM * 2;

    hipMemsetAsync(counts, 0, E * sizeof(int), stream);
    router_kernel<<<S, 256, 0, stream>>>(x, router_w, bias, counts, list, wlist);

    cast_bf16<<<(S * CDIM / 4 + 255) / 256, 256, 0, stream>>>((const float4*)x, xb, S * CDIM / 4);
    cast_bf16<<<(HS * CDIM / 4 + 255) / 256, 256, 0, stream>>>((const float4*)sgw, sgb, HS * CDIM / 4);
    cast_bf16<<<(HS * CDIM / 4 + 255) / 256, 256, 0, stream>>>((const float4*)suw, sub, HS * CDIM / 4);
    cast_bf16<<<(CDIM * HS / 4 + 255) / 256, 256, 0, stream>>>((const float4*)sdw, sdb, CDIM * HS / 4);

    transpose_cast<<<dim3(H / 32, CDIM / 32, E), dim3(32, 8), 0, stream>>>(gate_w, gwT, CDIM, H);
    transpose_cast<<<dim3(H / 32, CDIM / 32, E), dim3(32, 8), 0, stream>>>(up_w, uwT, CDIM, H);
    transpose_cast<<<dim3(CDIM / 32, H / 32, E), dim3(32, 8), 0, stream>>>(down_w, dwT, H, CDIM);

    gemm_shared_gateup<<<dim3(HS / 64, S / 128), 256, 0, stream>>>(xb, sgb, sub, shb);
    gemm_shared_down<<<dim3(CDIM / 64, S / 128), 256, 0, stream>>>(shb, sdb, out);
    gemm_routed_gateup<<<dim3(S / 128, H / 64, E), 256, 0, stream>>>(xb, gwT, uwT, counts, list, wlist, hbuf);
    gemm_routed_down<<<dim3(S / 128, CDIM / 64, E), 256, 0, stream>>>(hbuf, dwT, counts, list, dbuf);
    final_add<<<S * CDIM / 8 / 256, 256, 0, stream>>>(out, dbuf);
}

// Round 3
// 373.551 us; speedup vs baseline: 2.8663x; 1.0769x over previous
//
#include <hip/hip_runtime.h>
#include <hip/hip_bf16.h>
#include <math.h>

#define S 2048
#define CDIM 1024
#define H 256
#define HS 2048
#define E 16
#define GNUM 4
#define EPG 4
#define TOPK 4

typedef __attribute__((ext_vector_type(8))) short bfrag_t;   // 8 bf16 = 4 VGPRs
typedef __attribute__((ext_vector_type(4))) float facc_t;    // 4 fp32 acc
typedef __attribute__((ext_vector_type(4))) unsigned int u32x4;

__device__ __forceinline__ float sigmoidf_(float v) { return 1.f / (1.f + __expf(-v)); }

__device__ __forceinline__ unsigned short f2bf(float f) {
    union { float f; unsigned u; } v; v.f = f;
    unsigned r = v.u + 0x7FFFu + ((v.u >> 16) & 1u);   // round-to-nearest-even
    return (unsigned short)(r >> 16);
}
__device__ __forceinline__ float bf2f(unsigned short u) {
    union { unsigned u; float f; } v; v.u = ((unsigned)u) << 16; return v.f;
}

// ---------------------------------------------------------------------------
// K1: router — 16 tokens/block. Thread (t,e) computes logit[t][e] via float4
// dot; 16 threads then route 16 tokens in parallel (top-k is per-lane serial
// but across-token parallel). fp32 throughout so routing stays exact.
// ---------------------------------------------------------------------------
__global__ __launch_bounds__(256) void router_kernel(
    const float* __restrict__ x, const float* __restrict__ rw,
    const float* __restrict__ bias, int* __restrict__ counts,
    int* __restrict__ list, float* __restrict__ wlist)
{
    const int s0 = blockIdx.x * 16;
    const int tid = threadIdx.x;
    const int t = tid >> 4, e = tid & 15;
    const float4* xr = (const float4*)(x + (size_t)(s0 + t) * CDIM);
    const float4* wr = (const float4*)(rw + (size_t)e * CDIM);
    float acc = 0.f;
#pragma unroll 8
    for (int c = 0; c < CDIM / 4; ++c) {
        float4 xv = xr[c], wv = wr[c];
        acc += xv.x * wv.x + xv.y * wv.y + xv.z * wv.z + xv.w * wv.w;
    }
    __shared__ float lg[16][17];
    lg[t][e] = acc;
    __syncthreads();
    if (tid < 16) {
        const int s = s0 + tid;
        float sc[E], sb[E];
#pragma unroll
        for (int e2 = 0; e2 < E; ++e2) {
            sc[e2] = 1.f / (1.f + __expf(-lg[tid][e2]));
            sb[e2] = sc[e2] + bias[e2];
        }
        float gsc[GNUM];
#pragma unroll
        for (int g = 0; g < GNUM; ++g) {
            int b_ = g * EPG;
            int m1 = 0; float v1 = sb[b_];
#pragma unroll
            for (int j = 1; j < EPG; ++j) if (sb[b_ + j] > v1) { v1 = sb[b_ + j]; m1 = j; }
            float v2 = -1e30f;
#pragma unroll
            for (int j = 0; j < EPG; ++j) if (j != m1 && sb[b_ + j] > v2) v2 = sb[b_ + j];
            gsc[g] = v1 + v2;
        }
        int g1 = 0;
#pragma unroll
        for (int g = 1; g < GNUM; ++g) if (gsc[g] > gsc[g1]) g1 = g;
        int g2 = (g1 == 0) ? 1 : 0;
#pragma unroll
        for (int g = 0; g < GNUM; ++g) if (g != g1 && gsc[g] > gsc[g2]) g2 = g;
        bool allowed[E];
#pragma unroll
        for (int e2 = 0; e2 < E; ++e2) {
            int g = e2 >> 2;
            allowed[e2] = (g == g1) || (g == g2);
        }
        int idx[TOPK]; float wk[TOPK];
#pragma unroll
        for (int k = 0; k < TOPK; ++k) {
            int best = 0; float bv = -1e30f;
#pragma unroll
            for (int e2 = 0; e2 < E; ++e2)
                if (allowed[e2] && sb[e2] > bv) { bv = sb[e2]; best = e2; }
            allowed[best] = false;
            idx[k] = best;
            wk[k] = sc[best];
        }
        float inv = 1.f / (wk[0] + wk[1] + wk[2] + wk[3] + 1e-20f);
#pragma unroll
        for (int k = 0; k < TOPK; ++k) {
            int ee = idx[k];
            int pos = atomicAdd(&counts[ee], 1);
            list[ee * S + pos] = s | (k << 16);
            wlist[ee * S + pos] = wk[k] * inv;
        }
    }
}

// ---------------------------------------------------------------------------
// K2: elementwise fp32 -> bf16 cast (vectorized x4)
// ---------------------------------------------------------------------------
__global__ __launch_bounds__(256) void cast_bf16(
    const float4* __restrict__ src, unsigned short* __restrict__ dst, int n4)
{
    int i = blockIdx.x * 256 + threadIdx.x;
    if (i >= n4) return;
    float4 v = src[i];
    unsigned long long p = (unsigned long long)f2bf(v.x)
                         | ((unsigned long long)f2bf(v.y) << 16)
                         | ((unsigned long long)f2bf(v.z) << 32)
                         | ((unsigned long long)f2bf(v.w) << 48);
    ((unsigned long long*)dst)[i] = p;
}

// ---------------------------------------------------------------------------
// K3: tiled transpose + cast: src [z][R][Cc] fp32 -> dst [z][Cc][R] bf16
// ---------------------------------------------------------------------------
__global__ __launch_bounds__(256) void transpose_cast(
    const float* __restrict__ src, unsigned short* __restrict__ dst, int R, int Cc)
{
    __shared__ float t[32][33];
    const size_t mo = (size_t)blockIdx.z * R * Cc;
    src += mo; dst += mo;
    const int c0 = blockIdx.x * 32, r0 = blockIdx.y * 32;
    const int tx = threadIdx.x, ty = threadIdx.y;  // (32, 8)
#pragma unroll
    for (int i = 0; i < 32; i += 8)
        t[ty + i][tx] = src[(size_t)(r0 + ty + i) * Cc + c0 + tx];
    __syncthreads();
#pragma unroll
    for (int i = 0; i < 32; i += 8)
        dst[(size_t)(c0 + ty + i) * R + r0 + tx] = f2bf(t[tx][ty + i]);
}

// ---------------------------------------------------------------------------
// MFMA GEMM tiles: BM=128, BN=64, BK=32, block=256 (4 waves, 2x2), each wave
// 64x32 = 4x2 mfma_f32_16x16x32_bf16 tiles. LDS row stride 40 shorts.
// ---------------------------------------------------------------------------

// K4: shared expert gate+up fused SwiGLU -> shb bf16 [S][HS]
__global__ __launch_bounds__(256) void gemm_shared_gateup(
    const unsigned short* __restrict__ xb, const unsigned short* __restrict__ gb,
    const unsigned short* __restrict__ ub, unsigned short* __restrict__ shb)
{
    __shared__ __align__(16) unsigned short As[128][40];
    __shared__ __align__(16) unsigned short Bg[64][40];
    __shared__ __align__(16) unsigned short Bu[64][40];
    const int tid = threadIdx.x;
    const int r0 = blockIdx.y * 128;
    const int c0 = blockIdx.x * 64;
    const int lane = tid & 63, w = tid >> 6;
    const int wr = (w >> 1) * 64, wc = (w & 1) * 32;
    const int l15 = lane & 15, q = lane >> 4;
    const int srow = tid >> 2, sseg = tid & 3;
    const unsigned short* Ag = xb + (size_t)(r0 + srow) * CDIM + sseg * 8;
    const unsigned short* Gg = gb + (size_t)(c0 + srow) * CDIM + sseg * 8;
    const unsigned short* Ug = ub + (size_t)(c0 + srow) * CDIM + sseg * 8;
    facc_t accg[4][2], accu[4][2];
#pragma unroll
    for (int i = 0; i < 4; ++i)
#pragma unroll
        for (int j = 0; j < 2; ++j) { accg[i][j] = 0.f; accu[i][j] = 0.f; }
    for (int k0 = 0; k0 < CDIM; k0 += 32) {
        u32x4 a1 = *(const u32x4*)(Ag + k0);
        u32x4 a2 = *(const u32x4*)(Ag + (size_t)64 * CDIM + k0);
        u32x4 g1 = *(const u32x4*)(Gg + k0);
        u32x4 u1 = *(const u32x4*)(Ug + k0);
        __syncthreads();
        *(u32x4*)&As[srow][sseg * 8] = a1;
        *(u32x4*)&As[srow + 64][sseg * 8] = a2;
        *(u32x4*)&Bg[srow][sseg * 8] = g1;
        *(u32x4*)&Bu[srow][sseg * 8] = u1;
        __syncthreads();
        bfrag_t af[4], gf[2], uf[2];
#pragma unroll
        for (int i = 0; i < 4; ++i) af[i] = *(const bfrag_t*)&As[wr + i * 16 + l15][q * 8];
#pragma unroll
        for (int j = 0; j < 2; ++j) {
            gf[j] = *(const bfrag_t*)&Bg[wc + j * 16 + l15][q * 8];
            uf[j] = *(const bfrag_t*)&Bu[wc + j * 16 + l15][q * 8];
        }
#pragma unroll
        for (int i = 0; i < 4; ++i)
#pragma unroll
            for (int j = 0; j < 2; ++j) {
                accg[i][j] = __builtin_amdgcn_mfma_f32_16x16x32_bf16(af[i], gf[j], accg[i][j], 0, 0, 0);
                accu[i][j] = __builtin_amdgcn_mfma_f32_16x16x32_bf16(af[i], uf[j], accu[i][j], 0, 0, 0);
            }
    }
#pragma unroll
    for (int i = 0; i < 4; ++i)
#pragma unroll
        for (int j = 0; j < 2; ++j)
#pragma unroll
            for (int r = 0; r < 4; ++r) {
                int row = r0 + wr + i * 16 + q * 4 + r;
                int col = c0 + wc + j * 16 + l15;
                float g = accg[i][j][r], u = accu[i][j][r];
                shb[(size_t)row * HS + col] = f2bf(g * sigmoidf_(g) * u);
            }
}

// K5: shared expert down-proj -> out fp32 [S][CDIM] (initializes out)
__global__ __launch_bounds__(256) void gemm_shared_down(
    const unsigned short* __restrict__ shb, const unsigned short* __restrict__ db,
    float* __restrict__ out)
{
    __shared__ __align__(16) unsigned short As[128][40];
    __shared__ __align__(16) unsigned short Bs[64][40];
    const int tid = threadIdx.x;
    const int r0 = blockIdx.y * 128;
    const int c0 = blockIdx.x * 64;
    const int lane = tid & 63, w = tid >> 6;
    const int wr = (w >> 1) * 64, wc = (w & 1) * 32;
    const int l15 = lane & 15, q = lane >> 4;
    const int srow = tid >> 2, sseg = tid & 3;
    const unsigned short* Ag = shb + (size_t)(r0 + srow) * HS + sseg * 8;
    const unsigned short* Bgp = db + (size_t)(c0 + srow) * HS + sseg * 8;
    facc_t acc[4][2];
#pragma unroll
    for (int i = 0; i < 4; ++i)
#pragma unroll
        for (int j = 0; j < 2; ++j) acc[i][j] = 0.f;
    for (int k0 = 0; k0 < HS; k0 += 32) {
        u32x4 a1 = *(const u32x4*)(Ag + k0);
        u32x4 a2 = *(const u32x4*)(Ag + (size_t)64 * HS + k0);
        u32x4 b1 = *(const u32x4*)(Bgp + k0);
        __syncthreads();
        *(u32x4*)&As[srow][sseg * 8] = a1;
        *(u32x4*)&As[srow + 64][sseg * 8] = a2;
        *(u32x4*)&Bs[srow][sseg * 8] = b1;
        __syncthreads();
        bfrag_t af[4], bf[2];
#pragma unroll
        for (int i = 0; i < 4; ++i) af[i] = *(const bfrag_t*)&As[wr + i * 16 + l15][q * 8];
#pragma unroll
        for (int j = 0; j < 2; ++j) bf[j] = *(const bfrag_t*)&Bs[wc + j * 16 + l15][q * 8];
#pragma unroll
        for (int i = 0; i < 4; ++i)
#pragma unroll
            for (int j = 0; j < 2; ++j)
                acc[i][j] = __builtin_amdgcn_mfma_f32_16x16x32_bf16(af[i], bf[j], acc[i][j], 0, 0, 0);
    }
#pragma unroll
    for (int i = 0; i < 4; ++i)
#pragma unroll
        for (int j = 0; j < 2; ++j)
#pragma unroll
            for (int r = 0; r < 4; ++r) {
                int row = r0 + wr + i * 16 + q * 4 + r;
                int col = c0 + wc + j * 16 + l15;
                out[(size_t)row * CDIM + col] = acc[i][j][r];
            }
}

// K6: routed gate+up fused, gathered A rows, weighted SwiGLU -> hbuf bf16 [S*4][H]
__global__ __launch_bounds__(256) void gemm_routed_gateup(
    const unsigned short* __restrict__ xb, const unsigned short* __restrict__ gwT,
    const unsigned short* __restrict__ uwT, const int* __restrict__ counts,
    const int* __restrict__ list, const float* __restrict__ wlist,
    unsigned short* __restrict__ hbuf)
{
    const int e = blockIdx.z;
    const int n = counts[e];
    const int t0 = blockIdx.x * 128;
    if (t0 >= n) return;
    const int h0 = blockIdx.y * 64;
    __shared__ int toks[128];
    __shared__ int hrw[128];
    __shared__ float wv[128];
    __shared__ __align__(16) unsigned short As[128][40];
    __shared__ __align__(16) unsigned short Bg[64][40];
    __shared__ __align__(16) unsigned short Bu[64][40];
    const int tid = threadIdx.x;
    if (tid < 128) {
        int p = t0 + tid;
        if (p < n) {
            int pk = list[e * S + p];
            toks[tid] = pk & 0xFFFF;
            hrw[tid] = (pk & 0xFFFF) * TOPK + (pk >> 16);
            wv[tid] = wlist[e * S + p];
        } else { toks[tid] = 0; hrw[tid] = 0; wv[tid] = 0.f; }
    }
    __syncthreads();
    const int lane = tid & 63, w = tid >> 6;
    const int wr = (w >> 1) * 64, wc = (w & 1) * 32;
    const int l15 = lane & 15, q = lane >> 4;
    const int srow = tid >> 2, sseg = tid & 3;
    const unsigned short* A1 = xb + (size_t)toks[srow] * CDIM + sseg * 8;
    const unsigned short* A2 = xb + (size_t)toks[srow + 64] * CDIM + sseg * 8;
    const unsigned short* G1 = gwT + (size_t)e * H * CDIM + (size_t)(h0 + srow) * CDIM + sseg * 8;
    const unsigned short* U1 = uwT + (size_t)e * H * CDIM + (size_t)(h0 + srow) * CDIM + sseg * 8;
    facc_t accg[4][2], accu[4][2];
#pragma unroll
    for (int i = 0; i < 4; ++i)
#pragma unroll
        for (int j = 0; j < 2; ++j) { accg[i][j] = 0.f; accu[i][j] = 0.f; }
    for (int k0 = 0; k0 < CDIM; k0 += 32) {
        u32x4 a1 = *(const u32x4*)(A1 + k0);
        u32x4 a2 = *(const u32x4*)(A2 + k0);
        u32x4 g1 = *(const u32x4*)(G1 + k0);
        u32x4 u1 = *(const u32x4*)(U1 + k0);
        __syncthreads();
        *(u32x4*)&As[srow][sseg * 8] = a1;
        *(u32x4*)&As[srow + 64][sseg * 8] = a2;
        *(u32x4*)&Bg[srow][sseg * 8] = g1;
        *(u32x4*)&Bu[srow][sseg * 8] = u1;
        __syncthreads();
        bfrag_t af[4], gf[2], uf[2];
#pragma unroll
        for (int i = 0; i < 4; ++i) af[i] = *(const bfrag_t*)&As[wr + i * 16 + l15][q * 8];
#pragma unroll
        for (int j = 0; j < 2; ++j) {
            gf[j] = *(const bfrag_t*)&Bg[wc + j * 16 + l15][q * 8];
            uf[j] = *(const bfrag_t*)&Bu[wc + j * 16 + l15][q * 8];
        }
#pragma unroll
        for (int i = 0; i < 4; ++i)
#pragma unroll
            for (int j = 0; j < 2; ++j) {
                accg[i][j] = __builtin_amdgcn_mfma_f32_16x16x32_bf16(af[i], gf[j], accg[i][j], 0, 0, 0);
                accu[i][j] = __builtin_amdgcn_mfma_f32_16x16x32_bf16(af[i], uf[j], accu[i][j], 0, 0, 0);
            }
    }
#pragma unroll
    for (int i = 0; i < 4; ++i)
#pragma unroll
        for (int j = 0; j < 2; ++j)
#pragma unroll
            for (int r = 0; r < 4; ++r) {
                int li = wr + i * 16 + q * 4 + r;
                if (t0 + li < n) {
                    int col = h0 + wc + j * 16 + l15;
                    float g = accg[i][j][r], u = accu[i][j][r];
                    hbuf[(size_t)hrw[li] * H + col] = f2bf(wv[li] * g * sigmoidf_(g) * u);
                }
            }
}

// K7: routed down-proj, gathered A rows from hbuf -> dbuf bf16 [S*4][CDIM]
__global__ __launch_bounds__(256) void gemm_routed_down(
    const unsigned short* __restrict__ hbuf, const unsigned short* __restrict__ dwT,
    const int* __restrict__ counts, const int* __restrict__ list,
    unsigned short* __restrict__ dbuf)
{
    const int e = blockIdx.z;
    const int n = counts[e];
    const int t0 = blockIdx.x * 128;
    if (t0 >= n) return;
    const int c0 = blockIdx.y * 64;
    __shared__ int hrw[128];
    __shared__ __align__(16) unsigned short As[128][40];
    __shared__ __align__(16) unsigned short Bs[64][40];
    const int tid = threadIdx.x;
    if (tid < 128) {
        int p = t0 + tid;
        int pk = (p < n) ? list[e * S + p] : 0;
        hrw[tid] = (pk & 0xFFFF) * TOPK + (pk >> 16);
    }
    __syncthreads();
    const int lane = tid & 63, w = tid >> 6;
    const int wr = (w >> 1) * 64, wc = (w & 1) * 32;
    const int l15 = lane & 15, q = lane >> 4;
    const int srow = tid >> 2, sseg = tid & 3;
    const unsigned short* A1 = hbuf + (size_t)hrw[srow] * H + sseg * 8;
    const unsigned short* A2 = hbuf + (size_t)hrw[srow + 64] * H + sseg * 8;
    const unsigned short* B1 = dwT + (size_t)e * CDIM * H + (size_t)(c0 + srow) * H + sseg * 8;
    facc_t acc[4][2];
#pragma unroll
    for (int i = 0; i < 4; ++i)
#pragma unroll
        for (int j = 0; j < 2; ++j) acc[i][j] = 0.f;
    for (int k0 = 0; k0 < H; k0 += 32) {
        u32x4 a1 = *(const u32x4*)(A1 + k0);
        u32x4 a2 = *(const u32x4*)(A2 + k0);
        u32x4 b1 = *(const u32x4*)(B1 + k0);
        __syncthreads();
        *(u32x4*)&As[srow][sseg * 8] = a1;
        *(u32x4*)&As[srow + 64][sseg * 8] = a2;
        *(u32x4*)&Bs[srow][sseg * 8] = b1;
        __syncthreads();
        bfrag_t af[4], bf[2];
#pragma unroll
        for (int i = 0; i < 4; ++i) af[i] = *(const bfrag_t*)&As[wr + i * 16 + l15][q * 8];
#pragma unroll
        for (int j = 0; j < 2; ++j) bf[j] = *(const bfrag_t*)&Bs[wc + j * 16 + l15][q * 8];
#pragma unroll
        for (int i = 0; i < 4; ++i)
#pragma unroll
            for (int j = 0; j < 2; ++j)
                acc[i][j] = __builtin_amdgcn_mfma_f32_16x16x32_bf16(af[i], bf[j], acc[i][j], 0, 0, 0);
    }
#pragma unroll
    for (int i = 0; i < 4; ++i)
#pragma unroll
        for (int j = 0; j < 2; ++j)
#pragma unroll
            for (int r = 0; r < 4; ++r) {
                int li = wr + i * 16 + q * 4 + r;
                if (t0 + li < n) {
                    int col = c0 + wc + j * 16 + l15;
                    dbuf[(size_t)hrw[li] * CDIM + col] = f2bf(acc[i][j][r]);
                }
            }
}

// K8: out[s,c] += sum_k dbuf[s*4+k, c]
__global__ __launch_bounds__(256) void final_add(
    float* __restrict__ out, const unsigned short* __restrict__ dbuf)
{
    int i = blockIdx.x * 256 + threadIdx.x;   // 8 floats per thread
    int s = i >> 7;
    int co = (i & 127) << 3;
    float* op = out + (size_t)s * CDIM + co;
    float4 o0 = *(float4*)op, o1 = *(float4*)(op + 4);
#pragma unroll
    for (int k = 0; k < TOPK; ++k) {
        const unsigned short* dp = dbuf + ((size_t)s * TOPK + k) * CDIM + co;
        u32x4 v = *(const u32x4*)dp;
        o0.x += bf2f((unsigned short)(v.x));        o0.y += bf2f((unsigned short)(v.x >> 16));
        o0.z += bf2f((unsigned short)(v.y));        o0.w += bf2f((unsigned short)(v.y >> 16));
        o1.x += bf2f((unsigned short)(v.z));        o1.y += bf2f((unsigned short)(v.z >> 16));
        o1.z += bf2f((unsigned short)(v.w));        o1.w += bf2f((unsigned short)(v.w >> 16));
    }
    *(float4*)op = o0; *(float4*)(op + 4) = o1;
}

// ---------------------------------------------------------------------------
extern "C" void kernel_launch(void* const* d_in, const int* in_sizes, int n_in,
                              void* d_out, int out_size, void* d_ws, size_t ws_size,
                              hipStream_t stream)
{
    const float* x        = (const float*)d_in[0];
    const float* router_w = (const float*)d_in[1];
    const float* bias     = (const float*)d_in[2];
    const float* gate_w   = (const float*)d_in[3];
    const float* up_w     = (const float*)d_in[4];
    const float* down_w   = (const float*)d_in[5];
    const float* sgw      = (const float*)d_in[6];
    const float* suw      = (const float*)d_in[7];
    const float* sdw      = (const float*)d_in[8];
    float* out = (float*)d_out;

    char* ws = (char*)d_ws;
    size_t off = 0;
    int* counts = (int*)(ws + off);            off += 256;
    int* list   = (int*)(ws + off);            off += (size_t)E * S * 4;
    float* wlist = (float*)(ws + off);         off += (size_t)E * S * 4;
    unsigned short* xb  = (unsigned short*)(ws + off); off += (size_t)S * CDIM * 2;
    unsigned short* sgb = (unsigned short*)(ws + off); off += (size_t)HS * CDIM * 2;
    unsigned short* sub = (unsigned short*)(ws + off); off += (size_t)HS * CDIM * 2;
    unsigned short* sdb = (unsigned short*)(ws + off); off += (size_t)CDIM * HS * 2;
    unsigned short* gwT = (unsigned short*)(ws + off); off += (size_t)E * H * CDIM * 2;
    unsigned short* uwT = (unsigned short*)(ws + off); off += (size_t)E * H * CDIM * 2;
    unsigned short* dwT = (unsigned short*)(ws + off); off += (size_t)E * CDIM * H * 2;
    unsigned short* shb = (unsigned short*)(ws + off); off += (size_t)S * HS * 2;
    unsigned short* hbuf = (unsigned short*)(ws + off); off += (size_t)S * TOPK * H * 2;
    unsigned short* dbuf = (unsigned short*)(ws + off); off += (size_t)S * TOPK * CDIM * 2;

    hipMemsetAsync(counts, 0, E * sizeof(int), stream);
    router_kernel<<<S / 16, 256, 0, stream>>>(x, router_w, bias, counts, list, wlist);

    cast_bf16<<<(S * CDIM / 4 + 255) / 256, 256, 0, stream>>>((const float4*)x, xb, S * CDIM / 4);
    cast_bf16<<<(HS * CDIM / 4 + 255) / 256, 256, 0, stream>>>((const float4*)sgw, sgb, HS * CDIM / 4);
    cast_bf16<<<(HS * CDIM / 4 + 255) / 256, 256, 0, stream>>>((const float4*)suw, sub, HS * CDIM / 4);
    cast_bf16<<<(CDIM * HS / 4 + 255) / 256, 256, 0, stream>>>((const float4*)sdw, sdb, CDIM * HS / 4);

    transpose_cast<<<dim3(H / 32, CDIM / 32, E), dim3(32, 8), 0, stream>>>(gate_w, gwT, CDIM, H);
    transpose_cast<<<dim3(H / 32, CDIM / 32, E), dim3(32, 8), 0, stream>>>(up_w, uwT, CDIM, H);
    transpose_cast<<<dim3(CDIM / 32, H / 32, E), dim3(32, 8), 0, stream>>>(down_w, dwT, H, CDIM);

    gemm_shared_gateup<<<dim3(HS / 64, S / 128), 256, 0, stream>>>(xb, sgb, sub, shb);
    gemm_shared_down<<<dim3(CDIM / 64, S / 128), 256, 0, stream>>>(shb, sdb, out);
    gemm_routed_gateup<<<dim3(S / 128, H / 64, E), 256, 0, stream>>>(xb, gwT, uwT, counts, list, wlist, hbuf);
    gemm_routed_down<<<dim3(S / 128, CDIM / 64, E), 256, 0, stream>>>(hbuf, dwT, counts, list, dbuf);
    final_add<<<S * CDIM / 8 / 256, 256, 0, stream>>>(out, dbuf);
}

// Round 4
// 347.699 us; speedup vs baseline: 3.0794x; 1.0744x over previous
//
#include <hip/hip_runtime.h>
#include <hip/hip_bf16.h>
#include <math.h>

#define S 2048
#define CDIM 1024
#define H 256
#define HS 2048
#define E 16
#define GNUM 4
#define EPG 4
#define TOPK 4
#define KSLICES 8

typedef __attribute__((ext_vector_type(8))) short bfrag_t;   // 8 bf16 = 4 VGPRs
typedef __attribute__((ext_vector_type(4))) float facc_t;    // 4 fp32 acc
typedef __attribute__((ext_vector_type(4))) unsigned int u32x4;

__device__ __forceinline__ float sigmoidf_(float v) { return 1.f / (1.f + __expf(-v)); }

__device__ __forceinline__ unsigned short f2bf(float f) {
    union { float f; unsigned u; } v; v.f = f;
    unsigned r = v.u + 0x7FFFu + ((v.u >> 16) & 1u);   // round-to-nearest-even
    return (unsigned short)(r >> 16);
}
__device__ __forceinline__ float bf2f(unsigned short u) {
    union { unsigned u; float f; } v; v.u = ((unsigned)u) << 16; return v.f;
}

// ---------------------------------------------------------------------------
// K1a: split-K router logits. Grid (S/16, 8); thread (t,e) sums 128 elems of
// the dot product for token s0+t, expert e over c in [ks*128, ks*128+128).
// 1024 blocks -> 16 waves/CU, 32 float4 iters/thread.
// ---------------------------------------------------------------------------
__global__ __launch_bounds__(256) void logits_kernel(
    const float* __restrict__ x, const float* __restrict__ rw,
    float* __restrict__ lgpart)
{
    const int ks = blockIdx.y;
    const int s0 = blockIdx.x * 16;
    const int tid = threadIdx.x;
    const int t = tid & 15, e = tid >> 4;
    const float4* xp = (const float4*)(x + (size_t)(s0 + t) * CDIM + ks * (CDIM / KSLICES));
    const float4* wp = (const float4*)(rw + (size_t)e * CDIM + ks * (CDIM / KSLICES));
    float acc = 0.f;
#pragma unroll 8
    for (int c = 0; c < CDIM / KSLICES / 4; ++c) {
        float4 xv = xp[c], wv = wp[c];
        acc += xv.x * wv.x + xv.y * wv.y + xv.z * wv.z + xv.w * wv.w;
    }
    lgpart[((size_t)ks * S + s0 + t) * E + e] = acc;
}

// ---------------------------------------------------------------------------
// K1b: route one token per thread. Sums the 8 k-slices in fixed order, then
// grouped sigmoid top-k + atomic dispatch. 8 blocks x 256 threads.
// ---------------------------------------------------------------------------
__global__ __launch_bounds__(256) void route_kernel(
    const float* __restrict__ lgpart, const float* __restrict__ bias,
    int* __restrict__ counts, int* __restrict__ list, float* __restrict__ wlist)
{
    const int s = blockIdx.x * 256 + threadIdx.x;
    float lgv[E];
#pragma unroll
    for (int i = 0; i < E; ++i) lgv[i] = 0.f;
#pragma unroll
    for (int ks = 0; ks < KSLICES; ++ks) {
        const float4* p = (const float4*)(lgpart + ((size_t)ks * S + s) * E);
#pragma unroll
        for (int q = 0; q < 4; ++q) {
            float4 v = p[q];
            lgv[q * 4 + 0] += v.x; lgv[q * 4 + 1] += v.y;
            lgv[q * 4 + 2] += v.z; lgv[q * 4 + 3] += v.w;
        }
    }
    float sc[E], sb[E];
#pragma unroll
    for (int e2 = 0; e2 < E; ++e2) {
        sc[e2] = 1.f / (1.f + __expf(-lgv[e2]));
        sb[e2] = sc[e2] + bias[e2];
    }
    float gsc[GNUM];
#pragma unroll
    for (int g = 0; g < GNUM; ++g) {
        int b_ = g * EPG;
        int m1 = 0; float v1 = sb[b_];
#pragma unroll
        for (int j = 1; j < EPG; ++j) if (sb[b_ + j] > v1) { v1 = sb[b_ + j]; m1 = j; }
        float v2 = -1e30f;
#pragma unroll
        for (int j = 0; j < EPG; ++j) if (j != m1 && sb[b_ + j] > v2) v2 = sb[b_ + j];
        gsc[g] = v1 + v2;
    }
    int g1 = 0;
#pragma unroll
    for (int g = 1; g < GNUM; ++g) if (gsc[g] > gsc[g1]) g1 = g;
    int g2 = (g1 == 0) ? 1 : 0;
#pragma unroll
    for (int g = 0; g < GNUM; ++g) if (g != g1 && gsc[g] > gsc[g2]) g2 = g;
    bool allowed[E];
#pragma unroll
    for (int e2 = 0; e2 < E; ++e2) {
        int g = e2 >> 2;
        allowed[e2] = (g == g1) || (g == g2);
    }
    int idx[TOPK]; float wk[TOPK];
#pragma unroll
    for (int k = 0; k < TOPK; ++k) {
        int best = 0; float bv = -1e30f;
#pragma unroll
        for (int e2 = 0; e2 < E; ++e2)
            if (allowed[e2] && sb[e2] > bv) { bv = sb[e2]; best = e2; }
        allowed[best] = false;
        idx[k] = best;
        wk[k] = sc[best];
    }
    float inv = 1.f / (wk[0] + wk[1] + wk[2] + wk[3] + 1e-20f);
#pragma unroll
    for (int k = 0; k < TOPK; ++k) {
        int ee = idx[k];
        int pos = atomicAdd(&counts[ee], 1);
        list[ee * S + pos] = s | (k << 16);
        wlist[ee * S + pos] = wk[k] * inv;
    }
}

// ---------------------------------------------------------------------------
// K2: merged fp32 -> bf16 cast of 4 equal-size (2M elem) buffers.
// ---------------------------------------------------------------------------
struct CastArgs {
    const float4* src[4];
    unsigned long long* dst[4];
};
__global__ __launch_bounds__(256) void cast_bf16_x4(CastArgs a, int n4)
{
    int i = blockIdx.x * 256 + threadIdx.x;
    if (i >= n4) return;
    const float4* src = a.src[blockIdx.y];
    float4 v = src[i];
    unsigned long long p = (unsigned long long)f2bf(v.x)
                         | ((unsigned long long)f2bf(v.y) << 16)
                         | ((unsigned long long)f2bf(v.z) << 32)
                         | ((unsigned long long)f2bf(v.w) << 48);
    a.dst[blockIdx.y][i] = p;
}

// ---------------------------------------------------------------------------
// K3: tiled transpose + cast: src [z][R][Cc] fp32 -> dst [z][Cc][R] bf16
// ---------------------------------------------------------------------------
__global__ __launch_bounds__(256) void transpose_cast(
    const float* __restrict__ src, unsigned short* __restrict__ dst, int R, int Cc)
{
    __shared__ float t[32][33];
    const size_t mo = (size_t)blockIdx.z * R * Cc;
    src += mo; dst += mo;
    const int c0 = blockIdx.x * 32, r0 = blockIdx.y * 32;
    const int tx = threadIdx.x, ty = threadIdx.y;  // (32, 8)
#pragma unroll
    for (int i = 0; i < 32; i += 8)
        t[ty + i][tx] = src[(size_t)(r0 + ty + i) * Cc + c0 + tx];
    __syncthreads();
#pragma unroll
    for (int i = 0; i < 32; i += 8)
        dst[(size_t)(c0 + ty + i) * R + r0 + tx] = f2bf(t[tx][ty + i]);
}

// ---------------------------------------------------------------------------
// MFMA GEMMs: BM=128, BN=64, BK=32, 4 waves (2x2). Register prefetch: loads
// for tile k+1 issue after the second barrier, overlapping the MFMA compute
// of tile k (instead of stalling on vmcnt immediately before the LDS write).
// ---------------------------------------------------------------------------

// K4: shared expert gate+up fused SwiGLU -> shb bf16 [S][HS]
__global__ __launch_bounds__(256) void gemm_shared_gateup(
    const unsigned short* __restrict__ xb, const unsigned short* __restrict__ gb,
    const unsigned short* __restrict__ ub, unsigned short* __restrict__ shb)
{
    __shared__ __align__(16) unsigned short As[128][40];
    __shared__ __align__(16) unsigned short Bg[64][40];
    __shared__ __align__(16) unsigned short Bu[64][40];
    const int tid = threadIdx.x;
    const int r0 = blockIdx.y * 128;
    const int c0 = blockIdx.x * 64;
    const int lane = tid & 63, w = tid >> 6;
    const int wr = (w >> 1) * 64, wc = (w & 1) * 32;
    const int l15 = lane & 15, q = lane >> 4;
    const int srow = tid >> 2, sseg = tid & 3;
    const unsigned short* Ag = xb + (size_t)(r0 + srow) * CDIM + sseg * 8;
    const unsigned short* Gg = gb + (size_t)(c0 + srow) * CDIM + sseg * 8;
    const unsigned short* Ug = ub + (size_t)(c0 + srow) * CDIM + sseg * 8;
    facc_t accg[4][2], accu[4][2];
#pragma unroll
    for (int i = 0; i < 4; ++i)
#pragma unroll
        for (int j = 0; j < 2; ++j) { accg[i][j] = 0.f; accu[i][j] = 0.f; }
    u32x4 a1 = *(const u32x4*)(Ag);
    u32x4 a2 = *(const u32x4*)(Ag + (size_t)64 * CDIM);
    u32x4 g1 = *(const u32x4*)(Gg);
    u32x4 u1 = *(const u32x4*)(Ug);
    for (int k0 = 0; k0 < CDIM; k0 += 32) {
        __syncthreads();
        *(u32x4*)&As[srow][sseg * 8] = a1;
        *(u32x4*)&As[srow + 64][sseg * 8] = a2;
        *(u32x4*)&Bg[srow][sseg * 8] = g1;
        *(u32x4*)&Bu[srow][sseg * 8] = u1;
        __syncthreads();
        int kn = (k0 + 32 < CDIM) ? k0 + 32 : 0;
        a1 = *(const u32x4*)(Ag + kn);
        a2 = *(const u32x4*)(Ag + (size_t)64 * CDIM + kn);
        g1 = *(const u32x4*)(Gg + kn);
        u1 = *(const u32x4*)(Ug + kn);
        bfrag_t af[4], gf[2], uf[2];
#pragma unroll
        for (int i = 0; i < 4; ++i) af[i] = *(const bfrag_t*)&As[wr + i * 16 + l15][q * 8];
#pragma unroll
        for (int j = 0; j < 2; ++j) {
            gf[j] = *(const bfrag_t*)&Bg[wc + j * 16 + l15][q * 8];
            uf[j] = *(const bfrag_t*)&Bu[wc + j * 16 + l15][q * 8];
        }
#pragma unroll
        for (int i = 0; i < 4; ++i)
#pragma unroll
            for (int j = 0; j < 2; ++j) {
                accg[i][j] = __builtin_amdgcn_mfma_f32_16x16x32_bf16(af[i], gf[j], accg[i][j], 0, 0, 0);
                accu[i][j] = __builtin_amdgcn_mfma_f32_16x16x32_bf16(af[i], uf[j], accu[i][j], 0, 0, 0);
            }
    }
#pragma unroll
    for (int i = 0; i < 4; ++i)
#pragma unroll
        for (int j = 0; j < 2; ++j)
#pragma unroll
            for (int r = 0; r < 4; ++r) {
                int row = r0 + wr + i * 16 + q * 4 + r;
                int col = c0 + wc + j * 16 + l15;
                float g = accg[i][j][r], u = accu[i][j][r];
                shb[(size_t)row * HS + col] = f2bf(g * sigmoidf_(g) * u);
            }
}

// K5: shared expert down-proj -> out fp32 [S][CDIM] (initializes out)
__global__ __launch_bounds__(256) void gemm_shared_down(
    const unsigned short* __restrict__ shb, const unsigned short* __restrict__ db,
    float* __restrict__ out)
{
    __shared__ __align__(16) unsigned short As[128][40];
    __shared__ __align__(16) unsigned short Bs[64][40];
    const int tid = threadIdx.x;
    const int r0 = blockIdx.y * 128;
    const int c0 = blockIdx.x * 64;
    const int lane = tid & 63, w = tid >> 6;
    const int wr = (w >> 1) * 64, wc = (w & 1) * 32;
    const int l15 = lane & 15, q = lane >> 4;
    const int srow = tid >> 2, sseg = tid & 3;
    const unsigned short* Ag = shb + (size_t)(r0 + srow) * HS + sseg * 8;
    const unsigned short* Bgp = db + (size_t)(c0 + srow) * HS + sseg * 8;
    facc_t acc[4][2];
#pragma unroll
    for (int i = 0; i < 4; ++i)
#pragma unroll
        for (int j = 0; j < 2; ++j) acc[i][j] = 0.f;
    u32x4 a1 = *(const u32x4*)(Ag);
    u32x4 a2 = *(const u32x4*)(Ag + (size_t)64 * HS);
    u32x4 b1 = *(const u32x4*)(Bgp);
    for (int k0 = 0; k0 < HS; k0 += 32) {
        __syncthreads();
        *(u32x4*)&As[srow][sseg * 8] = a1;
        *(u32x4*)&As[srow + 64][sseg * 8] = a2;
        *(u32x4*)&Bs[srow][sseg * 8] = b1;
        __syncthreads();
        int kn = (k0 + 32 < HS) ? k0 + 32 : 0;
        a1 = *(const u32x4*)(Ag + kn);
        a2 = *(const u32x4*)(Ag + (size_t)64 * HS + kn);
        b1 = *(const u32x4*)(Bgp + kn);
        bfrag_t af[4], bf[2];
#pragma unroll
        for (int i = 0; i < 4; ++i) af[i] = *(const bfrag_t*)&As[wr + i * 16 + l15][q * 8];
#pragma unroll
        for (int j = 0; j < 2; ++j) bf[j] = *(const bfrag_t*)&Bs[wc + j * 16 + l15][q * 8];
#pragma unroll
        for (int i = 0; i < 4; ++i)
#pragma unroll
            for (int j = 0; j < 2; ++j)
                acc[i][j] = __builtin_amdgcn_mfma_f32_16x16x32_bf16(af[i], bf[j], acc[i][j], 0, 0, 0);
    }
#pragma unroll
    for (int i = 0; i < 4; ++i)
#pragma unroll
        for (int j = 0; j < 2; ++j)
#pragma unroll
            for (int r = 0; r < 4; ++r) {
                int row = r0 + wr + i * 16 + q * 4 + r;
                int col = c0 + wc + j * 16 + l15;
                out[(size_t)row * CDIM + col] = acc[i][j][r];
            }
}

// K6: routed gate+up fused, gathered A rows, weighted SwiGLU -> hbuf bf16 [S*4][H]
__global__ __launch_bounds__(256) void gemm_routed_gateup(
    const unsigned short* __restrict__ xb, const unsigned short* __restrict__ gwT,
    const unsigned short* __restrict__ uwT, const int* __restrict__ counts,
    const int* __restrict__ list, const float* __restrict__ wlist,
    unsigned short* __restrict__ hbuf)
{
    const int e = blockIdx.z;
    const int n = counts[e];
    const int t0 = blockIdx.x * 128;
    if (t0 >= n) return;
    const int h0 = blockIdx.y * 64;
    __shared__ int toks[128];
    __shared__ int hrw[128];
    __shared__ float wv[128];
    __shared__ __align__(16) unsigned short As[128][40];
    __shared__ __align__(16) unsigned short Bg[64][40];
    __shared__ __align__(16) unsigned short Bu[64][40];
    const int tid = threadIdx.x;
    if (tid < 128) {
        int p = t0 + tid;
        if (p < n) {
            int pk = list[e * S + p];
            toks[tid] = pk & 0xFFFF;
            hrw[tid] = (pk & 0xFFFF) * TOPK + (pk >> 16);
            wv[tid] = wlist[e * S + p];
        } else { toks[tid] = 0; hrw[tid] = 0; wv[tid] = 0.f; }
    }
    __syncthreads();
    const int lane = tid & 63, w = tid >> 6;
    const int wr = (w >> 1) * 64, wc = (w & 1) * 32;
    const int l15 = lane & 15, q = lane >> 4;
    const int srow = tid >> 2, sseg = tid & 3;
    const unsigned short* A1p = xb + (size_t)toks[srow] * CDIM + sseg * 8;
    const unsigned short* A2p = xb + (size_t)toks[srow + 64] * CDIM + sseg * 8;
    const unsigned short* G1p = gwT + (size_t)e * H * CDIM + (size_t)(h0 + srow) * CDIM + sseg * 8;
    const unsigned short* U1p = uwT + (size_t)e * H * CDIM + (size_t)(h0 + srow) * CDIM + sseg * 8;
    facc_t accg[4][2], accu[4][2];
#pragma unroll
    for (int i = 0; i < 4; ++i)
#pragma unroll
        for (int j = 0; j < 2; ++j) { accg[i][j] = 0.f; accu[i][j] = 0.f; }
    u32x4 a1 = *(const u32x4*)(A1p);
    u32x4 a2 = *(const u32x4*)(A2p);
    u32x4 g1 = *(const u32x4*)(G1p);
    u32x4 u1 = *(const u32x4*)(U1p);
    for (int k0 = 0; k0 < CDIM; k0 += 32) {
        __syncthreads();
        *(u32x4*)&As[srow][sseg * 8] = a1;
        *(u32x4*)&As[srow + 64][sseg * 8] = a2;
        *(u32x4*)&Bg[srow][sseg * 8] = g1;
        *(u32x4*)&Bu[srow][sseg * 8] = u1;
        __syncthreads();
        int kn = (k0 + 32 < CDIM) ? k0 + 32 : 0;
        a1 = *(const u32x4*)(A1p + kn);
        a2 = *(const u32x4*)(A2p + kn);
        g1 = *(const u32x4*)(G1p + kn);
        u1 = *(const u32x4*)(U1p + kn);
        bfrag_t af[4], gf[2], uf[2];
#pragma unroll
        for (int i = 0; i < 4; ++i) af[i] = *(const bfrag_t*)&As[wr + i * 16 + l15][q * 8];
#pragma unroll
        for (int j = 0; j < 2; ++j) {
            gf[j] = *(const bfrag_t*)&Bg[wc + j * 16 + l15][q * 8];
            uf[j] = *(const bfrag_t*)&Bu[wc + j * 16 + l15][q * 8];
        }
#pragma unroll
        for (int i = 0; i < 4; ++i)
#pragma unroll
            for (int j = 0; j < 2; ++j) {
                accg[i][j] = __builtin_amdgcn_mfma_f32_16x16x32_bf16(af[i], gf[j], accg[i][j], 0, 0, 0);
                accu[i][j] = __builtin_amdgcn_mfma_f32_16x16x32_bf16(af[i], uf[j], accu[i][j], 0, 0, 0);
            }
    }
#pragma unroll
    for (int i = 0; i < 4; ++i)
#pragma unroll
        for (int j = 0; j < 2; ++j)
#pragma unroll
            for (int r = 0; r < 4; ++r) {
                int li = wr + i * 16 + q * 4 + r;
                if (t0 + li < n) {
                    int col = h0 + wc + j * 16 + l15;
                    float g = accg[i][j][r], u = accu[i][j][r];
                    hbuf[(size_t)hrw[li] * H + col] = f2bf(wv[li] * g * sigmoidf_(g) * u);
                }
            }
}

// K7: routed down-proj, gathered A rows from hbuf -> dbuf bf16 [S*4][CDIM]
__global__ __launch_bounds__(256) void gemm_routed_down(
    const unsigned short* __restrict__ hbuf, const unsigned short* __restrict__ dwT,
    const int* __restrict__ counts, const int* __restrict__ list,
    unsigned short* __restrict__ dbuf)
{
    const int e = blockIdx.z;
    const int n = counts[e];
    const int t0 = blockIdx.x * 128;
    if (t0 >= n) return;
    const int c0 = blockIdx.y * 64;
    __shared__ int hrw[128];
    __shared__ __align__(16) unsigned short As[128][40];
    __shared__ __align__(16) unsigned short Bs[64][40];
    const int tid = threadIdx.x;
    if (tid < 128) {
        int p = t0 + tid;
        int pk = (p < n) ? list[e * S + p] : 0;
        hrw[tid] = (pk & 0xFFFF) * TOPK + (pk >> 16);
    }
    __syncthreads();
    const int lane = tid & 63, w = tid >> 6;
    const int wr = (w >> 1) * 64, wc = (w & 1) * 32;
    const int l15 = lane & 15, q = lane >> 4;
    const int srow = tid >> 2, sseg = tid & 3;
    const unsigned short* A1p = hbuf + (size_t)hrw[srow] * H + sseg * 8;
    const unsigned short* A2p = hbuf + (size_t)hrw[srow + 64] * H + sseg * 8;
    const unsigned short* B1p = dwT + (size_t)e * CDIM * H + (size_t)(c0 + srow) * H + sseg * 8;
    facc_t acc[4][2];
#pragma unroll
    for (int i = 0; i < 4; ++i)
#pragma unroll
        for (int j = 0; j < 2; ++j) acc[i][j] = 0.f;
    u32x4 a1 = *(const u32x4*)(A1p);
    u32x4 a2 = *(const u32x4*)(A2p);
    u32x4 b1 = *(const u32x4*)(B1p);
    for (int k0 = 0; k0 < H; k0 += 32) {
        __syncthreads();
        *(u32x4*)&As[srow][sseg * 8] = a1;
        *(u32x4*)&As[srow + 64][sseg * 8] = a2;
        *(u32x4*)&Bs[srow][sseg * 8] = b1;
        __syncthreads();
        int kn = (k0 + 32 < H) ? k0 + 32 : 0;
        a1 = *(const u32x4*)(A1p + kn);
        a2 = *(const u32x4*)(A2p + kn);
        b1 = *(const u32x4*)(B1p + kn);
        bfrag_t af[4], bf[2];
#pragma unroll
        for (int i = 0; i < 4; ++i) af[i] = *(const bfrag_t*)&As[wr + i * 16 + l15][q * 8];
#pragma unroll
        for (int j = 0; j < 2; ++j) bf[j] = *(const bfrag_t*)&Bs[wc + j * 16 + l15][q * 8];
#pragma unroll
        for (int i = 0; i < 4; ++i)
#pragma unroll
            for (int j = 0; j < 2; ++j)
                acc[i][j] = __builtin_amdgcn_mfma_f32_16x16x32_bf16(af[i], bf[j], acc[i][j], 0, 0, 0);
    }
#pragma unroll
    for (int i = 0; i < 4; ++i)
#pragma unroll
        for (int j = 0; j < 2; ++j)
#pragma unroll
            for (int r = 0; r < 4; ++r) {
                int li = wr + i * 16 + q * 4 + r;
                if (t0 + li < n) {
                    int col = c0 + wc + j * 16 + l15;
                    dbuf[(size_t)hrw[li] * CDIM + col] = f2bf(acc[i][j][r]);
                }
            }
}

// K8: out[s,c] += sum_k dbuf[s*4+k, c]
__global__ __launch_bounds__(256) void final_add(
    float* __restrict__ out, const unsigned short* __restrict__ dbuf)
{
    int i = blockIdx.x * 256 + threadIdx.x;   // 8 floats per thread
    int s = i >> 7;
    int co = (i & 127) << 3;
    float* op = out + (size_t)s * CDIM + co;
    float4 o0 = *(float4*)op, o1 = *(float4*)(op + 4);
#pragma unroll
    for (int k = 0; k < TOPK; ++k) {
        const unsigned short* dp = dbuf + ((size_t)s * TOPK + k) * CDIM + co;
        u32x4 v = *(const u32x4*)dp;
        o0.x += bf2f((unsigned short)(v.x));        o0.y += bf2f((unsigned short)(v.x >> 16));
        o0.z += bf2f((unsigned short)(v.y));        o0.w += bf2f((unsigned short)(v.y >> 16));
        o1.x += bf2f((unsigned short)(v.z));        o1.y += bf2f((unsigned short)(v.z >> 16));
        o1.z += bf2f((unsigned short)(v.w));        o1.w += bf2f((unsigned short)(v.w >> 16));
    }
    *(float4*)op = o0; *(float4*)(op + 4) = o1;
}

// ---------------------------------------------------------------------------
extern "C" void kernel_launch(void* const* d_in, const int* in_sizes, int n_in,
                              void* d_out, int out_size, void* d_ws, size_t ws_size,
                              hipStream_t stream)
{
    const float* x        = (const float*)d_in[0];
    const float* router_w = (const float*)d_in[1];
    const float* bias     = (const float*)d_in[2];
    const float* gate_w   = (const float*)d_in[3];
    const float* up_w     = (const float*)d_in[4];
    const float* down_w   = (const float*)d_in[5];
    const float* sgw      = (const float*)d_in[6];
    const float* suw      = (const float*)d_in[7];
    const float* sdw      = (const float*)d_in[8];
    float* out = (float*)d_out;

    char* ws = (char*)d_ws;
    size_t off = 0;
    int* counts = (int*)(ws + off);            off += 256;
    int* list   = (int*)(ws + off);            off += (size_t)E * S * 4;
    float* wlist = (float*)(ws + off);         off += (size_t)E * S * 4;
    unsigned short* xb  = (unsigned short*)(ws + off); off += (size_t)S * CDIM * 2;
    unsigned short* sgb = (unsigned short*)(ws + off); off += (size_t)HS * CDIM * 2;
    unsigned short* sub = (unsigned short*)(ws + off); off += (size_t)HS * CDIM * 2;
    unsigned short* sdb = (unsigned short*)(ws + off); off += (size_t)CDIM * HS * 2;
    unsigned short* gwT = (unsigned short*)(ws + off); off += (size_t)E * H * CDIM * 2;
    unsigned short* uwT = (unsigned short*)(ws + off); off += (size_t)E * H * CDIM * 2;
    unsigned short* dwT = (unsigned short*)(ws + off); off += (size_t)E * CDIM * H * 2;
    unsigned short* shb = (unsigned short*)(ws + off); off += (size_t)S * HS * 2;
    unsigned short* hbuf = (unsigned short*)(ws + off); off += (size_t)S * TOPK * H * 2;
    unsigned short* dbuf = (unsigned short*)(ws + off); off += (size_t)S * TOPK * CDIM * 2;
    // lgpart (8*S*E floats = 1 MiB) aliases dbuf: consumed by route_kernel
    // long before gemm_routed_down writes dbuf (same stream, serial).
    float* lgpart = (float*)dbuf;

    hipMemsetAsync(counts, 0, E * sizeof(int), stream);
    logits_kernel<<<dim3(S / 16, KSLICES), 256, 0, stream>>>(x, router_w, lgpart);
    route_kernel<<<S / 256, 256, 0, stream>>>(lgpart, bias, counts, list, wlist);

    CastArgs ca;
    ca.src[0] = (const float4*)x;   ca.dst[0] = (unsigned long long*)xb;
    ca.src[1] = (const float4*)sgw; ca.dst[1] = (unsigned long long*)sgb;
    ca.src[2] = (const float4*)suw; ca.dst[2] = (unsigned long long*)sub;
    ca.src[3] = (const float4*)sdw; ca.dst[3] = (unsigned long long*)sdb;
    cast_bf16_x4<<<dim3(S * CDIM / 4 / 256, 4), 256, 0, stream>>>(ca, S * CDIM / 4);

    transpose_cast<<<dim3(H / 32, CDIM / 32, E), dim3(32, 8), 0, stream>>>(gate_w, gwT, CDIM, H);
    transpose_cast<<<dim3(H / 32, CDIM / 32, E), dim3(32, 8), 0, stream>>>(up_w, uwT, CDIM, H);
    transpose_cast<<<dim3(CDIM / 32, H / 32, E), dim3(32, 8), 0, stream>>>(down_w, dwT, H, CDIM);

    gemm_shared_gateup<<<dim3(HS / 64, S / 128), 256, 0, stream>>>(xb, sgb, sub, shb);
    gemm_shared_down<<<dim3(CDIM / 64, S / 128), 256, 0, stream>>>(shb, sdb, out);
    gemm_routed_gateup<<<dim3(S / 128, H / 64, E), 256, 0, stream>>>(xb, gwT, uwT, counts, list, wlist, hbuf);
    gemm_routed_down<<<dim3(S / 128, CDIM / 64, E), 256, 0, stream>>>(hbuf, dwT, counts, list, dbuf);
    final_add<<<S * CDIM / 8 / 256, 256, 0, stream>>>(out, dbuf);
}